// Round 1
// baseline (255.482 us; speedup 1.0000x reference)
//
#include <hip/hip_runtime.h>
#include <cstdint>

#define NM   4096
#define NP   32768
#define NSEG 1024
#define GD   2304
#define HID  150
#define NPAD 160
#define KG32 72                      // GD/32
#define SEG_ELEMS (KG32 * 10 * 512)  // 368640 bf16 elems per packed W segment

typedef unsigned short u16;
typedef short s16x8 __attribute__((ext_vector_type(8)));   // 8 bf16 in 4 VGPRs
typedef float f32x4 __attribute__((ext_vector_type(4)));

struct alignas(16) U4 { uint32_t a[4]; };

union Frag {
    uint32_t u[4];
    s16x8    v;
};

// round-to-nearest (ties away) fp32 -> bf16, two at a time packed into a dword
__device__ inline uint32_t pack2bf(float lo, float hi) {
    uint32_t a = __builtin_bit_cast(uint32_t, lo);
    uint32_t b = __builtin_bit_cast(uint32_t, hi);
    return ((a + 0x8000u) >> 16) | ((b + 0x8000u) & 0xffff0000u);
}

__device__ inline f32x4 mfma16(s16x8 a, s16x8 b, f32x4 c) {
    return __builtin_amdgcn_mfma_f32_16x16x32_bf16(a, b, c, 0, 0, 0);
}

// elementwise bf16 product of two 8-elem chunks -> bf16 A-fragment
__device__ inline s16x8 prodpack(U4 iu, U4 ju) {
    Frag f;
#pragma unroll
    for (int m = 0; m < 4; ++m) {
        uint32_t x = iu.a[m], y = ju.a[m];
        float lo = __builtin_bit_cast(float, x << 16) *
                   __builtin_bit_cast(float, y << 16);
        float hi = __builtin_bit_cast(float, x & 0xffff0000u) *
                   __builtin_bit_cast(float, y & 0xffff0000u);
        f.u[m] = pack2bf(lo, hi);
    }
    return f.v;
}

#define GLOAD_LDS(gp, lp)                                                      \
    __builtin_amdgcn_global_load_lds(                                          \
        (__attribute__((address_space(1))) void*)(void*)(gp),                  \
        (__attribute__((address_space(3))) void*)(lp), 16, 0, 0)

// ---------------------------------------------------------------------------
// Pack W1 blocks into MFMA B-fragment order.
// Segment 0: W1_prod (rows 4608..6911), 1: W1_i (0..2303), 2: W1_j (2304..4607)
// Layout per segment: [kg32][nf(10)][lane(64)][j(8)] bf16, zero-pad cols>=150.
// B-frag mapping (16x16x32): n = lane&15, k = (lane>>4)*8 + j.
// ---------------------------------------------------------------------------
__global__ void prep_pack_kernel(const float* __restrict__ W1,
                                 u16* __restrict__ wpack) {
    int idx = blockIdx.x * 256 + threadIdx.x;
    if (idx >= 3 * SEG_ELEMS) return;
    int segi = idx / SEG_ELEMS;
    int t    = idx - segi * SEG_ELEMS;
    int kg   = t / 5120;
    int r    = t - kg * 5120;
    int nf   = r >> 9;
    int q    = r & 511;
    int lane = q >> 3, j = q & 7;
    int kl = kg * 32 + ((lane >> 4) << 3) + j;
    int n  = nf * 16 + (lane & 15);
    int kbase = (segi == 0) ? 2 * GD : ((segi == 1) ? 0 : GD);
    float v = (n < HID) ? W1[(size_t)(kbase + kl) * HID + n] : 0.f;
    uint32_t a = __builtin_bit_cast(uint32_t, v);
    wpack[idx] = (u16)((a + 0x7fffu + ((a >> 16) & 1u)) >> 16);  // RNE
}

// phib[s][n] = phi(s) @ W1_phi[:,n] + b1[n]  (zero for n>=150); w2pad likewise
__global__ void prep_tables_kernel(const float* __restrict__ spk,
                                   const float* __restrict__ W1,
                                   const float* __restrict__ b1,
                                   const float* __restrict__ W2,
                                   float* __restrict__ phib,
                                   float* __restrict__ w2pad) {
    int t = threadIdx.x;
    if (t < 3 * NPAD) {
        int s = t / NPAD, n = t - s * NPAD;
        float a = 0.f;
        if (n < HID) {
            for (int d = 0; d < 20; ++d)
                a = fmaf(spk[s * 20 + d], W1[(size_t)(3 * GD + d) * HID + n], a);
            a += b1[n];
        }
        phib[t] = a;
    } else if (t < 4 * NPAD) {
        int n = t - 3 * NPAD;
        w2pad[n] = (n < HID) ? W2[n] : 0.f;
    }
}

// ---------------------------------------------------------------------------
// APre[m, 0:160)   = g_i[m] @ W1_i   (bf16 MFMA)
// APre[m, 160:320) = g_i[m] @ W1_j
// ng==0 blocks also emit the bf16 copy of g_i (gbf) as a side product.
// Grid (64 Mtiles, 2 ng) x 128 thr. Wave = 32 rows x 160 cols.
// ---------------------------------------------------------------------------
__launch_bounds__(128)
__global__ void gemm_pre_kernel(const float* __restrict__ gi,
                                const u16* __restrict__ wpackIJ,
                                u16* __restrict__ gbf,
                                float* __restrict__ APre) {
    const int tid = threadIdx.x;
    const int wave = tid >> 6, lane = tid & 63;
    const int quad = lane >> 4, l15 = lane & 15;
    const int mt = blockIdx.x, ng = blockIdx.y;
    const u16* wp = wpackIJ + (size_t)ng * SEG_ELEMS;
    const int rowbase = mt * 64 + wave * 32;

    __shared__ u16 Bt[10240];  // 20 KB: one k64 W tile in frag order

    f32x4 acc[2][10];
#pragma unroll
    for (int a = 0; a < 2; ++a)
#pragma unroll
        for (int b = 0; b < 10; ++b) acc[a][b] = (f32x4){0.f, 0.f, 0.f, 0.f};

    const float* ap0 = gi + (size_t)(rowbase + l15) * GD + quad * 8;
    const float* ap1 = ap0 + (size_t)16 * GD;
    u16* gb0 = gbf + (size_t)(rowbase + l15) * GD + quad * 8;
    u16* gb1 = gb0 + (size_t)16 * GD;
    const bool emit = (ng == 0);

    for (int kt = 0; kt < 36; ++kt) {
        __syncthreads();
        const char* gsrc  = ((const char*)wp) + (size_t)kt * 20480;
        char*       lbase = ((char*)Bt) + wave * 1024;
#pragma unroll
        for (int c = 0; c < 10; ++c)
            GLOAD_LDS(gsrc + c * 2048 + wave * 1024 + lane * 16, lbase + c * 2048);
        __syncthreads();

#pragma unroll
        for (int s = 0; s < 2; ++s) {
            const int kk = kt * 64 + s * 32;
            Frag a0, a1;
            {
                float4 x0 = *(const float4*)(ap0 + kk);
                float4 x1 = *(const float4*)(ap0 + kk + 4);
                a0.u[0] = pack2bf(x0.x, x0.y); a0.u[1] = pack2bf(x0.z, x0.w);
                a0.u[2] = pack2bf(x1.x, x1.y); a0.u[3] = pack2bf(x1.z, x1.w);
                float4 y0 = *(const float4*)(ap1 + kk);
                float4 y1 = *(const float4*)(ap1 + kk + 4);
                a1.u[0] = pack2bf(y0.x, y0.y); a1.u[1] = pack2bf(y0.z, y0.w);
                a1.u[2] = pack2bf(y1.x, y1.y); a1.u[3] = pack2bf(y1.z, y1.w);
            }
            if (emit) {
                *(U4*)(gb0 + kk) = *(const U4*)a0.u;
                *(U4*)(gb1 + kk) = *(const U4*)a1.u;
            }
#pragma unroll
            for (int nf = 0; nf < 10; ++nf) {
                s16x8 b = *(const s16x8*)(const void*)(Bt + s * 5120 + nf * 512 + lane * 8);
                acc[0][nf] = mfma16(a0.v, b, acc[0][nf]);
                acc[1][nf] = mfma16(a1.v, b, acc[1][nf]);
            }
        }
    }

    // C/D layout: col = lane&15, row = (lane>>4)*4 + reg
    const int colbase = ng * NPAD + l15;
#pragma unroll
    for (int mf = 0; mf < 2; ++mf)
#pragma unroll
        for (int nf = 0; nf < 10; ++nf)
#pragma unroll
            for (int r = 0; r < 4; ++r) {
                int row = rowbase + mf * 16 + quad * 4 + r;
                APre[(size_t)row * 320 + colbase + nf * 16] = acc[mf][nf][r];
            }
}

// ---------------------------------------------------------------------------
// Main pair kernel: scores[p] = s_i + s_j + b2 + W2 . relu( (i*j)@W1_prod
//                                + APre_i + APre_j + phib[spk] )
// Grid 512 x 128 thr. Wave = 32 pairs x 160 cols; A built in-register.
// ---------------------------------------------------------------------------
__launch_bounds__(128)
__global__ void gemm_pairs_kernel(const u16* __restrict__ gbf,
                                  const u16* __restrict__ wpackP,
                                  const float* __restrict__ APre,
                                  const float* __restrict__ phib,
                                  const float* __restrict__ w2pad,
                                  const float* __restrict__ mscore,
                                  const float* __restrict__ b2,
                                  const int* __restrict__ mids,
                                  const int* __restrict__ aids,
                                  const int* __restrict__ slab,
                                  float* __restrict__ scores) {
    const int tid = threadIdx.x;
    const int wave = tid >> 6, lane = tid & 63;
    const int quad = lane >> 4, l15 = lane & 15;
    const int base = blockIdx.x * 64 + wave * 32;

    __shared__ u16 Bt[10240];

    f32x4 acc[2][10];
#pragma unroll
    for (int a = 0; a < 2; ++a)
#pragma unroll
        for (int b = 0; b < 10; ++b) acc[a][b] = (f32x4){0.f, 0.f, 0.f, 0.f};

    const int p0 = base + l15, p1 = base + 16 + l15;
    const u16* ip0 = gbf + (size_t)mids[p0] * GD + quad * 8;
    const u16* jp0 = gbf + (size_t)aids[p0] * GD + quad * 8;
    const u16* ip1 = gbf + (size_t)mids[p1] * GD + quad * 8;
    const u16* jp1 = gbf + (size_t)aids[p1] * GD + quad * 8;

    // software-pipelined A gather (one substep ahead)
    U4 iu0 = *(const U4*)ip0, ju0 = *(const U4*)jp0;
    U4 iu1 = *(const U4*)ip1, ju1 = *(const U4*)jp1;

    for (int u = 0; u < 72; ++u) {
        if ((u & 1) == 0) {
            __syncthreads();
            const int kt = u >> 1;
            const char* gsrc = ((const char*)wpackP) + (size_t)kt * 20480;
#pragma unroll
            for (int c = 0; c < 10; ++c)
                GLOAD_LDS(gsrc + c * 2048 + wave * 1024 + lane * 16,
                          ((char*)Bt) + c * 2048 + wave * 1024);
            __syncthreads();
        }
        U4 ci0 = iu0, cj0 = ju0, ci1 = iu1, cj1 = ju1;
        if (u < 71) {
            const int off = (u + 1) * 32;
            iu0 = *(const U4*)(ip0 + off); ju0 = *(const U4*)(jp0 + off);
            iu1 = *(const U4*)(ip1 + off); ju1 = *(const U4*)(jp1 + off);
        }
        s16x8 a0 = prodpack(ci0, cj0);
        s16x8 a1 = prodpack(ci1, cj1);
        const int s = u & 1;
#pragma unroll
        for (int nf = 0; nf < 10; ++nf) {
            s16x8 b = *(const s16x8*)(const void*)(Bt + s * 5120 + nf * 512 + lane * 8);
            acc[0][nf] = mfma16(a0, b, acc[0][nf]);
            acc[1][nf] = mfma16(a1, b, acc[1][nf]);
        }
    }

    // Epilogue: bias + relu + W2-dot + cross-lane reduce, write scores
    float w2v[10];
#pragma unroll
    for (int nf = 0; nf < 10; ++nf) w2v[nf] = w2pad[nf * 16 + l15];
    const float b2v = b2[0];

#pragma unroll
    for (int mf = 0; mf < 2; ++mf)
#pragma unroll
        for (int r = 0; r < 4; ++r) {
            const int p  = base + mf * 16 + quad * 4 + r;
            const int mi = mids[p], ai = aids[p], sp = slab[p];
            const float* Ai = APre + (size_t)mi * 320;
            const float* Bj = APre + (size_t)ai * 320 + NPAD;
            const float* Ph = phib + sp * NPAD;
            float partial = 0.f;
#pragma unroll
            for (int nf = 0; nf < 10; ++nf) {
                const int c = nf * 16 + l15;
                float h = acc[mf][nf][r] + Ai[c] + Bj[c] + Ph[c];
                h = fmaxf(h, 0.f);
                partial = fmaf(h, w2v[nf], partial);
            }
            partial += __shfl_xor(partial, 1);
            partial += __shfl_xor(partial, 2);
            partial += __shfl_xor(partial, 4);
            partial += __shfl_xor(partial, 8);
            if (l15 == 0)
                scores[p] = partial + b2v + mscore[mi] + mscore[ai];
        }
}

// ---------------------------------------------------------------------------
// Ragged per-span softmax with epsilon logit 0. One wave per segment;
// segment_ids is sorted -> binary search the range.
// ---------------------------------------------------------------------------
__global__ void seg_softmax_kernel(const float* __restrict__ scores,
                                   const int* __restrict__ seg,
                                   float* __restrict__ out) {
    const int s = blockIdx.x;
    const int lane = threadIdx.x;
    int lo = 0, hi = NP;
    while (lo < hi) { int mid = (lo + hi) >> 1; if (seg[mid] < s) lo = mid + 1; else hi = mid; }
    const int start = lo;
    int lo2 = start, hi2 = NP;
    while (lo2 < hi2) { int mid = (lo2 + hi2) >> 1; if (seg[mid] <= s) lo2 = mid + 1; else hi2 = mid; }
    const int end = lo2;

    float m = 0.f;  // epsilon logit 0 participates in the max
    for (int i = start + lane; i < end; i += 64) m = fmaxf(m, scores[i]);
#pragma unroll
    for (int msk = 1; msk < 64; msk <<= 1) m = fmaxf(m, __shfl_xor(m, msk));

    float sum = 0.f;
    for (int i = start + lane; i < end; i += 64) sum += __expf(scores[i] - m);
#pragma unroll
    for (int msk = 1; msk < 64; msk <<= 1) sum += __shfl_xor(sum, msk);

    const float epse = __expf(-m);
    const float inv  = 1.f / (sum + epse);
    for (int i = start + lane; i < end; i += 64) out[i] = __expf(scores[i] - m) * inv;
    if (lane == 0) out[NP + s] = epse * inv;
}

// ---------------------------------------------------------------------------
extern "C" void kernel_launch(void* const* d_in, const int* in_sizes, int n_in,
                              void* d_out, int out_size, void* d_ws, size_t ws_size,
                              hipStream_t stream) {
    const float* gi     = (const float*)d_in[0];
    const float* mscore = (const float*)d_in[1];
    const float* spk    = (const float*)d_in[2];
    const float* W1     = (const float*)d_in[3];
    const float* b1     = (const float*)d_in[4];
    const float* W2     = (const float*)d_in[5];
    const float* b2     = (const float*)d_in[6];
    const int*   mids   = (const int*)d_in[7];
    const int*   aids   = (const int*)d_in[8];
    const int*   slab   = (const int*)d_in[9];
    const int*   segs   = (const int*)d_in[10];
    float* out = (float*)d_out;

    char* w = (char*)d_ws;
    u16*   gbf    = (u16*)w;                               // 18,874,368 B
    u16*   wpack  = (u16*)(w + 18874368);                  //  2,211,840 B (3 segs)
    float* APre   = (float*)(w + 21086208);                //  5,242,880 B
    float* scores = (float*)(w + 26329088);                //    131,072 B
    float* phib   = (float*)(w + 26460160);                //      1,920 B
    float* w2pad  = (float*)(w + 26462080);                //        640 B

    prep_pack_kernel<<<dim3((3 * SEG_ELEMS + 255) / 256), dim3(256), 0, stream>>>(W1, wpack);
    prep_tables_kernel<<<dim3(1), dim3(640), 0, stream>>>(spk, W1, b1, W2, phib, w2pad);
    gemm_pre_kernel<<<dim3(64, 2), dim3(128), 0, stream>>>(gi, wpack + SEG_ELEMS, gbf, APre);
    gemm_pairs_kernel<<<dim3(512), dim3(128), 0, stream>>>(gbf, wpack, APre, phib, w2pad,
                                                           mscore, b2, mids, aids, slab, scores);
    seg_softmax_kernel<<<dim3(NSEG), dim3(64), 0, stream>>>(scores, segs, out);
}